// Round 1
// baseline (124.773 us; speedup 1.0000x reference)
//
#include <hip/hip_runtime.h>
#include <math.h>

// B=128, NU=32, NT=64, H=128, OUT_F=16, N_U=4096, N_A=8192
// Per-batch-local GNN (fully bipartite within batch; segment-means are
// per-batch means). R12 = R11 + two changes:
//   (1) Weight prep kernel: all 13 fp32 [k][n] mats packed ONCE per launch
//       into bf16 MFMA-A-fragment order in workspace. Main kernel's per-stage
//       A-fetch is now 4 coalesced global_load_dwordx4 (was 32 strided scalar
//       fp32 loads + ~128 VALU f2bf convert per wave per stage).
//   (2) Same-XCD psync pairing: b = blk&127, half = blk>>7, partner = blk^128
//       (128 % 8 == 0 -> same XCD under round-robin dispatch) so flag spins +
//       partial-sum exchange hit the local L2 instead of crossing to MALL.
//   Everything else identical to R11:
//   256 blocks x 512 threads (8 waves, n-split 8): block (b,half) owns
//   16 hu + 32 ha rows in LDS end-to-end. All bias vectors staged to LDS once.
//   Cross-block: 4 colsum partials (sc1 write-through, write-once,
//   first-touch-after-sync) + 3 pairwise seq-flag syncs. Relaxed atomics
//   only; no inv/wbl2 anywhere.
// Workspace: 32KB flags + 512KB partials + 416KB packed weights = 983040 B.

using frag  = __attribute__((ext_vector_type(8))) short;   // 8 x bf16
using f32x4 = __attribute__((ext_vector_type(4))) float;

#define LDST 136
#define SCOPE_AGT __HIP_MEMORY_SCOPE_AGENT

__device__ __forceinline__ float  bf2f(ushort u) { return __uint_as_float(((unsigned)u) << 16); }
__device__ __forceinline__ ushort f2bf(float f) {
    unsigned u = __float_as_uint(f);
    u += 0x7fff + ((u >> 16) & 1);            // RNE
    return (ushort)(u >> 16);
}
__device__ __forceinline__ void gst4_sc(void* p, unsigned v) {   // write-through to MALL
    asm volatile("global_store_dword %0, %1, off sc1" :: "v"(p), "v"(v) : "memory");
}

struct GP {
    const float *uf, *noise, *b_ue, *W_t, *b_t;
    const float *bias6[6];
    const float *Wn, *bn;
    const ushort *Wp;          // packed bf16 A-frag weights: 13 mats x 16384 ushorts
    float *out;
    float *pE, *pA0, *pU0, *pA1;   // per-block 128-f colsum partials
    unsigned *flg;
};
// Wp mat slots: 0,1 ca_aggr L0/L1; 2,3 ca_self; 4,5 ca_comb; 6,7 cu_aggr;
//               8,9 cu_self; 10,11 cu_comb; 12 W_ue

struct PrepP { const float* Wm[13]; ushort* Wp; };

// Wp[((m*4+kc)*8 + w)*512 + l*8 + j] = bf16( W[kc*32 + (l>>4)*8 + j][w*16 + (l&15)] )
// One thread per output ushort; writes fully coalesced. 416 blocks x 512 = 13*16384.
__global__ __launch_bounds__(512) void k_prep(PrepP Q)
{
    const int t  = blockIdx.x * 512 + threadIdx.x;
    const int j  = t & 7, l = (t >> 3) & 63, w = (t >> 9) & 7,
              kc = (t >> 12) & 3, m = t >> 14;
    const float v = Q.Wm[m][(kc * 32 + (l >> 4) * 8 + j) * 128 + w * 16 + (l & 15)];
    Q.Wp[t] = f2bf(v);
}

// ---- pairwise sync: single-writer seq flags ----
__device__ __forceinline__ void psync(unsigned* myf, unsigned* pf, unsigned s) {
    asm volatile("s_waitcnt vmcnt(0)" ::: "memory");   // drain my sc1 stores
    __syncthreads();
    if (threadIdx.x == 0) {
        __hip_atomic_store(myf, s, __ATOMIC_RELAXED, SCOPE_AGT);
        while (__hip_atomic_load(pf, __ATOMIC_RELAXED, SCOPE_AGT) < s)
            __builtin_amdgcn_s_sleep(1);
    }
    __syncthreads();
}

// ---- A-fragment fetch: 4 coalesced 16B loads from packed weights ----
struct AF { frag f[4]; };
__device__ __forceinline__ AF ldA(const ushort* __restrict__ Wp, int mat, int tid)
{
    AF a;
    const ushort* base = Wp + ((size_t)mat << 14) + (tid << 3);   // tid = wave*64+lane
#pragma unroll
    for (int kc = 0; kc < 4; ++kc)
        a.f[kc] = *(const frag*)(base + (kc << 12));
    return a;
}

// ---- MLP stage: wave w owns n-cols [16w,16w+16); MT m-tiles; LDS bias ----
template<int MT, bool MEANADD>
__device__ __forceinline__ void mlp_stage(const AF& A, const ushort* Xl, ushort* Yl,
    const float* biasL, const float* meanL, int n0, int l15, int q)
{
    const float4 bv = *(const float4*)(biasL + n0 + q * 4);
    float4 mv = {0.f, 0.f, 0.f, 0.f};
    if (MEANADD) mv = *(const float4*)(meanL + n0 + q * 4);
#pragma unroll
    for (int mt = 0; mt < MT; ++mt) {
        frag Bv[4];
#pragma unroll
        for (int kc = 0; kc < 4; ++kc)
            Bv[kc] = *(const frag*)(Xl + (mt * 16 + l15) * LDST + kc * 32 + q * 8);
        f32x4 acc = {0.f, 0.f, 0.f, 0.f};
#pragma unroll
        for (int kc = 0; kc < 4; ++kc)
            acc = __builtin_amdgcn_mfma_f32_16x16x32_bf16(A.f[kc], Bv[kc], acc, 0, 0, 0);
        float v0 = acc[0] + bv.x, v1 = acc[1] + bv.y, v2 = acc[2] + bv.z, v3 = acc[3] + bv.w;
        v0 = v0 > 0.f ? v0 : 0.f; v1 = v1 > 0.f ? v1 : 0.f;
        v2 = v2 > 0.f ? v2 : 0.f; v3 = v3 > 0.f ? v3 : 0.f;
        if (MEANADD) { v0 += mv.x; v1 += mv.y; v2 += mv.z; v3 += mv.w; }
        ushort4 o = { f2bf(v0), f2bf(v1), f2bf(v2), f2bf(v3) };
        *(ushort4*)(Yl + (mt * 16 + l15) * LDST + n0 + q * 4) = o;
    }
}

// ---- column sum over ROWS rows -> own LDS dst + sc1 global partial ----
template<int ROWS>
__device__ __forceinline__ void colsum(const ushort* buf, float* redL,
                                       float* ownDst, float* __restrict__ gDst)
{
    const int t = threadIdx.x, g = t >> 7, col = t & 127;
    float s = 0.f;
#pragma unroll
    for (int r = g; r < ROWS; r += 4) s += bf2f(buf[r * LDST + col]);
    redL[g * 128 + col] = s;
    __syncthreads();
    if (t < 128) {
        float tot = redL[t] + redL[128 + t] + redL[256 + t] + redL[384 + t];
        ownDst[t] = tot;
        gst4_sc(gDst + t, __float_as_uint(tot));
    }
    __syncthreads();
}

__global__ __launch_bounds__(512, 1) void k_gnn(GP P)
{
    __shared__ __align__(16) ushort HU[16 * LDST];   // hu -> (aliased) hu2
    __shared__ __align__(16) ushort HA[32 * LDST];   // ha -> (aliased) ha2
    __shared__ __align__(16) ushort T0[32 * LDST];
    __shared__ __align__(16) ushort T1[32 * LDST];
    __shared__ __align__(16) float  biasL[1792];     // all bias vectors
    __shared__ __align__(16) float  redL[512];
    __shared__ __align__(16) float  meanP[128], meanQ[128], antL[128];

    const int blk = blockIdx.x, tid = threadIdx.x;
    // same-XCD pairing: partner = blk ^ 128 (same XCD under round-robin %8)
    const int b = blk & 127, half = blk >> 7, prt = blk ^ 128;
    const int lane = tid & 63, wave = tid >> 6;
    const int q = lane >> 4, l15 = lane & 15;
    const int n0 = wave * 16;
    unsigned* myf = P.flg + blk * 32;
    unsigned* prf = P.flg + prt * 32;

    // ---- first A fetch (embed weights), then stage inputs ----
    AF An = ldA(P.Wp, 12, tid);

    {   // 16 uf rows -> T0 (512 float4 chunks exactly)
        const int r = tid >> 5, k4 = tid & 31;
        const float4 v = *(const float4*)(P.uf + (size_t)(b * 32 + half * 16 + r) * 128 + k4 * 4);
        ushort4 o = { f2bf(v.x), f2bf(v.y), f2bf(v.z), f2bf(v.w) };
        *(ushort4*)(T0 + r * LDST + k4 * 4) = o;
    }
#pragma unroll
    for (int c = tid; c < 1024; c += 512) {   // 32 noise rows -> HA (ant added later)
        const int r = c >> 5, k4 = c & 31;
        const float4 v = *(const float4*)(P.noise + (size_t)(b * 64 + half * 32 + r) * 128 + k4 * 4);
        ushort4 o = { f2bf(v.x), f2bf(v.y), f2bf(v.z), f2bf(v.w) };
        *(ushort4*)(HA + r * LDST + k4 * 4) = o;
    }
    // bias vectors -> LDS (once)
    if (tid < 128) biasL[tid] = P.b_ue[tid];
    if (tid < 128) biasL[1664 + tid] = P.b_t[tid];
#pragma unroll
    for (int r = 0; r < 6; ++r)
        if (tid < 256) biasL[128 + r * 256 + tid] = P.bias6[r][tid];
    __syncthreads();

    AF A;
    // S1 embed: T0 -> HU
    A = An; An = ldA(P.Wp, 0, tid);
    mlp_stage<1, false>(A, T0, HU, biasL + 0, nullptr, n0, l15, q);
    __syncthreads();
    colsum<16>(HU, redL, meanP, P.pE + blk * 128);          // E partial
    // S2-S3 it0 aggr-hu
    A = An; An = ldA(P.Wp, 1, tid);
    mlp_stage<1, false>(A, HU, T0, biasL + 128, nullptr, n0, l15, q);
    __syncthreads();
    A = An; An = ldA(P.Wp, 6, tid);
    mlp_stage<1, false>(A, T0, T1, biasL + 256, nullptr, n0, l15, q);
    __syncthreads();
    colsum<16>(T1, redL, meanQ, P.pA0 + blk * 128);         // A0 partial
    psync(myf, prf, 1u);

    // ant = relu(meanE @ W_t + b_t); HA += ant ; combine meanQ (A0) too
    if (tid < 128) {
        meanP[tid] = (meanP[tid] + P.pE[prt * 128 + tid]) * (1.f / 32.f);
        meanQ[tid] = (meanQ[tid] + P.pA0[prt * 128 + tid]) * (1.f / 32.f);
    }
    __syncthreads();
    {
        const int g = tid >> 7, col = tid & 127;
        float s = 0.f;
#pragma unroll 4
        for (int k = g * 32; k < g * 32 + 32; ++k) s += meanP[k] * P.W_t[k * 128 + col];
        redL[g * 128 + col] = s;
    }
    __syncthreads();
    if (tid < 128) {
        float a = biasL[1664 + tid] + redL[tid] + redL[128 + tid] + redL[256 + tid] + redL[384 + tid];
        antL[tid] = a > 0.f ? a : 0.f;
    }
    __syncthreads();
#pragma unroll
    for (int c = tid; c < 1024; c += 512) {
        const int r = c >> 5, k4 = c & 31;
        ushort4 h = *(ushort4*)(HA + r * LDST + k4 * 4);
        ushort4 o = { f2bf(bf2f(h.x) + antL[k4 * 4 + 0]), f2bf(bf2f(h.y) + antL[k4 * 4 + 1]),
                      f2bf(bf2f(h.z) + antL[k4 * 4 + 2]), f2bf(bf2f(h.w) + antL[k4 * 4 + 3]) };
        *(ushort4*)(HA + r * LDST + k4 * 4) = o;
    }
    __syncthreads();

    // S4-S5 it0 aggr-ha
    A = An; An = ldA(P.Wp, 7, tid);
    mlp_stage<2, false>(A, HA, T0, biasL + 896, nullptr, n0, l15, q);
    __syncthreads();
    A = An; An = ldA(P.Wp, 2, tid);
    mlp_stage<2, false>(A, T0, T1, biasL + 1024, nullptr, n0, l15, q);
    __syncthreads();
    colsum<32>(T1, redL, meanP, P.pU0 + blk * 128);         // U0 partial
    // S6 self-ha L0 (independent of partner -> overlap psync2)
    A = An; An = ldA(P.Wp, 3, tid);
    mlp_stage<2, false>(A, HA, T0, biasL + 384, nullptr, n0, l15, q);
    __syncthreads();
    psync(myf, prf, 2u);
    if (tid < 128)
        meanP[tid] = (meanP[tid] + P.pU0[prt * 128 + tid]) * (1.f / 64.f);
    __syncthreads();
    // S7-S9 it0 comb-ha ; HA := ha2
    A = An; An = ldA(P.Wp, 4, tid);
    mlp_stage<2, true >(A, T0, T1, biasL + 512, meanQ, n0, l15, q);
    __syncthreads();
    A = An; An = ldA(P.Wp, 5, tid);
    mlp_stage<2, false>(A, T1, T0, biasL + 640, nullptr, n0, l15, q);
    __syncthreads();
    A = An; An = ldA(P.Wp, 8, tid);
    mlp_stage<2, false>(A, T0, HA, biasL + 768, nullptr, n0, l15, q);
    __syncthreads();
    // S10-S13 it0 comb-hu ; HU := hu2
    A = An; An = ldA(P.Wp, 9, tid);
    mlp_stage<1, false>(A, HU, T0, biasL + 1152, nullptr, n0, l15, q);
    __syncthreads();
    A = An; An = ldA(P.Wp, 10, tid);
    mlp_stage<1, true >(A, T0, T1, biasL + 1280, meanP, n0, l15, q);
    __syncthreads();
    A = An; An = ldA(P.Wp, 11, tid);
    mlp_stage<1, false>(A, T1, T0, biasL + 1408, nullptr, n0, l15, q);
    __syncthreads();
    A = An; An = ldA(P.Wp, 0, tid);
    mlp_stage<1, false>(A, T0, HU, biasL + 1536, nullptr, n0, l15, q);
    __syncthreads();

    // S14-S15 it1 aggr-hu2 (it1 cu-side is dead)
    A = An; An = ldA(P.Wp, 1, tid);
    mlp_stage<1, false>(A, HU, T0, biasL + 128, nullptr, n0, l15, q);
    __syncthreads();
    A = An; An = ldA(P.Wp, 2, tid);
    mlp_stage<1, false>(A, T0, T1, biasL + 256, nullptr, n0, l15, q);
    __syncthreads();
    colsum<16>(T1, redL, meanQ, P.pA1 + blk * 128);         // A1 partial
    // S16 self-ha2 L0 (overlap psync3)
    A = An; An = ldA(P.Wp, 3, tid);
    mlp_stage<2, false>(A, HA, T0, biasL + 384, nullptr, n0, l15, q);
    __syncthreads();
    psync(myf, prf, 3u);
    if (tid < 128)
        meanQ[tid] = (meanQ[tid] + P.pA1[prt * 128 + tid]) * (1.f / 32.f);
    __syncthreads();
    // S17-S19 it1 comb-ha2 -> T1   (chain 3 -> 4 -> 5)
    A = An; An = ldA(P.Wp, 4, tid);
    mlp_stage<2, true >(A, T0, T1, biasL + 512, meanQ, n0, l15, q);
    __syncthreads();
    A = An; An = ldA(P.Wp, 5, tid);
    mlp_stage<2, false>(A, T1, T0, biasL + 640, nullptr, n0, l15, q);
    __syncthreads();
    A = An;
    mlp_stage<2, false>(A, T0, T1, biasL + 768, nullptr, n0, l15, q);
    __syncthreads();

    // ---- final: out = normalize(T1 @ Wn + bn); 32 rows x 16 cols = 512 ----
    float* WnS = (float*)T0;                               // 8 KB <= T0
    *(float4*)(WnS + tid * 4) = *(const float4*)(P.Wn + tid * 4);
    __syncthreads();
    {
        const int row = tid >> 4, j = tid & 15;
        float acc = P.bn[j];
        const ushort* h = T1 + row * LDST;
#pragma unroll 8
        for (int k = 0; k < 128; ++k) acc += bf2f(h[k]) * WnS[k * 16 + j];
        const float other = __shfl_xor(acc, 8);            // re<->im partner, same wave
        const float mag = sqrtf(acc * acc + other * other);
        P.out[(size_t)(b * 64 + half * 32 + row) * 16 + j] = acc / mag;
    }
}

extern "C" void kernel_launch(void* const* d_in, const int* in_sizes, int n_in,
                              void* d_out, int out_size, void* d_ws, size_t ws_size,
                              hipStream_t stream)
{
    GP P;
    P.uf    = (const float*)d_in[0];
    P.noise = (const float*)d_in[1];
    const float* W_ue = (const float*)d_in[6];
    P.b_ue  = (const float*)d_in[7];
    P.W_t   = (const float*)d_in[8];
    P.b_t   = (const float*)d_in[9];
    const float* caW[3] = {(const float*)d_in[10], (const float*)d_in[12], (const float*)d_in[14]};
    const float* cab[3] = {(const float*)d_in[11], (const float*)d_in[13], (const float*)d_in[15]};
    const float* cuW[3] = {(const float*)d_in[16], (const float*)d_in[18], (const float*)d_in[20]};
    const float* cub[3] = {(const float*)d_in[17], (const float*)d_in[19], (const float*)d_in[21]};
    P.Wn  = (const float*)d_in[22];
    P.bn  = (const float*)d_in[23];
    P.out = (float*)d_out;

    PrepP Q;
    Q.Wm[0]  = caW[0]; Q.Wm[1]  = caW[0] + 16384;
    Q.Wm[2]  = caW[1]; Q.Wm[3]  = caW[1] + 16384;
    Q.Wm[4]  = caW[2]; Q.Wm[5]  = caW[2] + 16384;
    Q.Wm[6]  = cuW[0]; Q.Wm[7]  = cuW[0] + 16384;
    Q.Wm[8]  = cuW[1]; Q.Wm[9]  = cuW[1] + 16384;
    Q.Wm[10] = cuW[2]; Q.Wm[11] = cuW[2] + 16384;
    Q.Wm[12] = W_ue;
    P.bias6[0] = cab[0]; P.bias6[1] = cab[1]; P.bias6[2] = cab[2];
    P.bias6[3] = cub[0]; P.bias6[4] = cub[1]; P.bias6[5] = cub[2];

    char* w = (char*)d_ws;
    P.flg = (unsigned*)w;                       // 256 flags, 128 B apart (32 KB)
    P.pE  = (float*)(w + 32768);                // 4 partial arrays, 256*128 f each
    P.pA0 = P.pE  + 256 * 128;
    P.pU0 = P.pA0 + 256 * 128;
    P.pA1 = P.pU0 + 256 * 128;
    ushort* Wp = (ushort*)(w + 32768 + 4 * 256 * 128 * 4);   // 13 * 32 KB packed weights
    Q.Wp = Wp;
    P.Wp = Wp;

    k_prep<<<dim3(416), dim3(512), 0, stream>>>(Q);
    hipMemsetAsync(w, 0, 32768, stream);        // flags only
    k_gnn<<<dim3(256), dim3(512), 0, stream>>>(P);
}

// Round 2
// 121.864 us; speedup vs baseline: 1.0239x; 1.0239x over previous
//
#include <hip/hip_runtime.h>
#include <math.h>

// B=128, NU=32, NT=64, H=128, OUT_F=16, N_U=4096, N_A=8192
// Per-batch-local GNN (fully bipartite within batch; segment-means are
// per-batch means). R13 = R12 + three changes:
//   (1) Colsums FUSED into the producing mlp_stage: wave w owns cols
//       [16w,16w+16) exclusively, so per-col sums complete in-wave via
//       4 __shfl_xor steps; lanes l15==0 write the LDS partial + sc1
//       global partial. Removes 4 colsum routines (8 barriers + scalar
//       ds_read_u16 passes).
//   (2) Memset dispatch folded into k_prep (blocks 0-15 zero the 32 KB
//       flag region); 3 dispatches -> 2. Prep vectorized to uint4 writes
//       (52 blocks x 512).
//   (3) Epilogue bf16 pack via v_cvt_pk_bf16_f32 (RNE, 2 vals/instr)
//       instead of manual f2bf bit-twiddling (~4 VALU/val).
//   Everything else identical to R12:
//   256 blocks x 512 threads (8 waves, n-split 8): block (b,half) owns
//   16 hu + 32 ha rows in LDS end-to-end. Packed bf16 A-frag weights from
//   prep kernel; A prefetched one stage ahead. Same-XCD psync pairing
//   (partner = blk ^ 128). Relaxed atomics only; no inv/wbl2.
// Workspace: 32KB flags + 512KB partials + 416KB packed weights.

using frag  = __attribute__((ext_vector_type(8))) short;   // 8 x bf16
using f32x4 = __attribute__((ext_vector_type(4))) float;

#define LDST 136
#define SCOPE_AGT __HIP_MEMORY_SCOPE_AGENT

__device__ __forceinline__ float  bf2f(ushort u) { return __uint_as_float(((unsigned)u) << 16); }
__device__ __forceinline__ ushort f2bf(float f) {
    unsigned u = __float_as_uint(f);
    u += 0x7fff + ((u >> 16) & 1);            // RNE
    return (ushort)(u >> 16);
}
__device__ __forceinline__ unsigned cvtpk(float lo, float hi) {   // [hi:lo] bf16 pair, RNE
    unsigned r;
    asm("v_cvt_pk_bf16_f32 %0, %1, %2" : "=v"(r) : "v"(lo), "v"(hi));
    return r;
}
__device__ __forceinline__ void gst16_sc(void* p, f32x4 v) {   // write-through to MALL
    asm volatile("global_store_dwordx4 %0, %1, off sc1" :: "v"(p), "v"(v) : "memory");
}

struct GP {
    const float *uf, *noise, *b_ue, *W_t, *b_t;
    const float *bias6[6];
    const float *Wn, *bn;
    const ushort *Wp;          // packed bf16 A-frag weights: 13 mats x 16384 ushorts
    float *out;
    float *pE, *pA0, *pU0, *pA1;   // per-block 128-f colsum partials
    unsigned *flg;
};
// Wp mat slots: 0,1 ca_aggr L0/L1; 2,3 ca_self; 4,5 ca_comb; 6,7 cu_aggr;
//               8,9 cu_self; 10,11 cu_comb; 12 W_ue

struct PrepP { const float* Wm[13]; ushort* Wp; unsigned* flg; };

// Wp[((m*4+kc)*8 + w)*512 + l*8 + j] = bf16( W[kc*32 + (l>>4)*8 + j][w*16 + (l&15)] )
// One thread per 8 output ushorts (uint4 store). 52 blocks x 512 = 13*16384/8.
// Blocks 0-15 additionally zero the 32 KB psync flag region.
__global__ __launch_bounds__(512) void k_prep(PrepP Q)
{
    const int tid = threadIdx.x, blk = blockIdx.x;
    if (blk < 16) Q.flg[blk * 512 + tid] = 0;
    const int e = (blk * 512 + tid) * 8;
    const int l = (e >> 3) & 63, w = (e >> 9) & 7, kc = (e >> 12) & 3, m = e >> 14;
    const float* src = Q.Wm[m] + (kc * 32 + (l >> 4) * 8) * 128 + w * 16 + (l & 15);
    ushort h[8];
#pragma unroll
    for (int j = 0; j < 8; ++j) h[j] = f2bf(src[j * 128]);
    uint4 o = { (unsigned)h[0] | ((unsigned)h[1] << 16), (unsigned)h[2] | ((unsigned)h[3] << 16),
                (unsigned)h[4] | ((unsigned)h[5] << 16), (unsigned)h[6] | ((unsigned)h[7] << 16) };
    *(uint4*)(Q.Wp + e) = o;
}

// ---- pairwise sync: single-writer seq flags ----
__device__ __forceinline__ void psync(unsigned* myf, unsigned* pf, unsigned s) {
    asm volatile("s_waitcnt vmcnt(0)" ::: "memory");   // drain my sc1 stores
    __syncthreads();
    if (threadIdx.x == 0) {
        __hip_atomic_store(myf, s, __ATOMIC_RELAXED, SCOPE_AGT);
        while (__hip_atomic_load(pf, __ATOMIC_RELAXED, SCOPE_AGT) < s)
            __builtin_amdgcn_s_sleep(1);
    }
    __syncthreads();
}

// ---- A-fragment fetch: 4 coalesced 16B loads from packed weights ----
struct AF { frag f[4]; };
__device__ __forceinline__ AF ldA(const ushort* __restrict__ Wp, int mat, int tid)
{
    AF a;
    const ushort* base = Wp + ((size_t)mat << 14) + (tid << 3);   // tid = wave*64+lane
#pragma unroll
    for (int kc = 0; kc < 4; ++kc)
        a.f[kc] = *(const frag*)(base + (kc << 12));
    return a;
}

// ---- MLP stage: wave w owns n-cols [16w,16w+16); MT m-tiles; LDS bias ----
// CS: additionally col-sum the stored (post-relu) values over all MT*16 rows,
// writing the wave's 16-col partial to csL (LDS) and csG (global, sc1).
template<int MT, bool MEANADD, bool CS>
__device__ __forceinline__ void mlp_stage(const AF& A, const ushort* Xl, ushort* Yl,
    const float* biasL, const float* meanL, float* csL, float* __restrict__ csG,
    int n0, int l15, int q)
{
    const float4 bv = *(const float4*)(biasL + n0 + q * 4);
    float4 mv = {0.f, 0.f, 0.f, 0.f};
    if (MEANADD) mv = *(const float4*)(meanL + n0 + q * 4);
    float cs0 = 0.f, cs1 = 0.f, cs2 = 0.f, cs3 = 0.f;
#pragma unroll
    for (int mt = 0; mt < MT; ++mt) {
        frag Bv[4];
#pragma unroll
        for (int kc = 0; kc < 4; ++kc)
            Bv[kc] = *(const frag*)(Xl + (mt * 16 + l15) * LDST + kc * 32 + q * 8);
        f32x4 acc = {0.f, 0.f, 0.f, 0.f};
#pragma unroll
        for (int kc = 0; kc < 4; ++kc)
            acc = __builtin_amdgcn_mfma_f32_16x16x32_bf16(A.f[kc], Bv[kc], acc, 0, 0, 0);
        float v0 = acc[0] + bv.x, v1 = acc[1] + bv.y, v2 = acc[2] + bv.z, v3 = acc[3] + bv.w;
        v0 = v0 > 0.f ? v0 : 0.f; v1 = v1 > 0.f ? v1 : 0.f;
        v2 = v2 > 0.f ? v2 : 0.f; v3 = v3 > 0.f ? v3 : 0.f;
        if (MEANADD) { v0 += mv.x; v1 += mv.y; v2 += mv.z; v3 += mv.w; }
        if (CS) { cs0 += v0; cs1 += v1; cs2 += v2; cs3 += v3; }
        uint2 o = { cvtpk(v0, v1), cvtpk(v2, v3) };
        *(uint2*)(Yl + (mt * 16 + l15) * LDST + n0 + q * 4) = o;
    }
    if (CS) {
        // reduce over the 16 l15 lanes of this q-group (cols are wave-exclusive)
#pragma unroll
        for (int m = 1; m <= 8; m <<= 1) {
            cs0 += __shfl_xor(cs0, m); cs1 += __shfl_xor(cs1, m);
            cs2 += __shfl_xor(cs2, m); cs3 += __shfl_xor(cs3, m);
        }
        if (l15 == 0) {
            f32x4 t = { cs0, cs1, cs2, cs3 };
            *(f32x4*)(csL + n0 + q * 4) = t;
            gst16_sc(csG + n0 + q * 4, t);
        }
    }
}

__global__ __launch_bounds__(512, 1) void k_gnn(GP P)
{
    __shared__ __align__(16) ushort HU[16 * LDST];   // hu -> (aliased) hu2
    __shared__ __align__(16) ushort HA[32 * LDST];   // ha -> (aliased) ha2
    __shared__ __align__(16) ushort T0[32 * LDST];
    __shared__ __align__(16) ushort T1[32 * LDST];
    __shared__ __align__(16) float  biasL[1792];     // all bias vectors
    __shared__ __align__(16) float  redL[512];
    __shared__ __align__(16) float  meanP[128], meanQ[128], antL[128];

    const int blk = blockIdx.x, tid = threadIdx.x;
    // same-XCD pairing: partner = blk ^ 128 (same XCD under round-robin %8)
    const int b = blk & 127, half = blk >> 7, prt = blk ^ 128;
    const int lane = tid & 63, wave = tid >> 6;
    const int q = lane >> 4, l15 = lane & 15;
    const int n0 = wave * 16;
    unsigned* myf = P.flg + blk * 32;
    unsigned* prf = P.flg + prt * 32;

    // ---- first A fetch (embed weights), then stage inputs ----
    AF An = ldA(P.Wp, 12, tid);

    {   // 16 uf rows -> T0 (512 float4 chunks exactly)
        const int r = tid >> 5, k4 = tid & 31;
        const float4 v = *(const float4*)(P.uf + (size_t)(b * 32 + half * 16 + r) * 128 + k4 * 4);
        uint2 o = { cvtpk(v.x, v.y), cvtpk(v.z, v.w) };
        *(uint2*)(T0 + r * LDST + k4 * 4) = o;
    }
#pragma unroll
    for (int c = tid; c < 1024; c += 512) {   // 32 noise rows -> HA (ant added later)
        const int r = c >> 5, k4 = c & 31;
        const float4 v = *(const float4*)(P.noise + (size_t)(b * 64 + half * 32 + r) * 128 + k4 * 4);
        uint2 o = { cvtpk(v.x, v.y), cvtpk(v.z, v.w) };
        *(uint2*)(HA + r * LDST + k4 * 4) = o;
    }
    // bias vectors -> LDS (once)
    if (tid < 128) biasL[tid] = P.b_ue[tid];
    if (tid < 128) biasL[1664 + tid] = P.b_t[tid];
#pragma unroll
    for (int r = 0; r < 6; ++r)
        if (tid < 256) biasL[128 + r * 256 + tid] = P.bias6[r][tid];
    __syncthreads();

    AF A;
    // S1 embed: T0 -> HU (+fused E colsum)
    A = An; An = ldA(P.Wp, 0, tid);
    mlp_stage<1, false, true>(A, T0, HU, biasL + 0, nullptr, meanP, P.pE + blk * 128, n0, l15, q);
    __syncthreads();
    // S2-S3 it0 aggr-hu (+fused A0 colsum on S3)
    A = An; An = ldA(P.Wp, 1, tid);
    mlp_stage<1, false, false>(A, HU, T0, biasL + 128, nullptr, nullptr, nullptr, n0, l15, q);
    __syncthreads();
    A = An; An = ldA(P.Wp, 6, tid);
    mlp_stage<1, false, true>(A, T0, T1, biasL + 256, nullptr, meanQ, P.pA0 + blk * 128, n0, l15, q);
    __syncthreads();
    psync(myf, prf, 1u);

    // ant = relu(meanE @ W_t + b_t); HA += ant ; combine meanQ (A0) too
    if (tid < 128) {
        meanP[tid] = (meanP[tid] + P.pE[prt * 128 + tid]) * (1.f / 32.f);
        meanQ[tid] = (meanQ[tid] + P.pA0[prt * 128 + tid]) * (1.f / 32.f);
    }
    __syncthreads();
    {
        const int g = tid >> 7, col = tid & 127;
        float s = 0.f;
#pragma unroll 4
        for (int k = g * 32; k < g * 32 + 32; ++k) s += meanP[k] * P.W_t[k * 128 + col];
        redL[g * 128 + col] = s;
    }
    __syncthreads();
    if (tid < 128) {
        float a = biasL[1664 + tid] + redL[tid] + redL[128 + tid] + redL[256 + tid] + redL[384 + tid];
        antL[tid] = a > 0.f ? a : 0.f;
    }
    __syncthreads();
#pragma unroll
    for (int c = tid; c < 1024; c += 512) {
        const int r = c >> 5, k4 = c & 31;
        ushort4 h = *(ushort4*)(HA + r * LDST + k4 * 4);
        uint2 o = { cvtpk(bf2f(h.x) + antL[k4 * 4 + 0], bf2f(h.y) + antL[k4 * 4 + 1]),
                    cvtpk(bf2f(h.z) + antL[k4 * 4 + 2], bf2f(h.w) + antL[k4 * 4 + 3]) };
        *(uint2*)(HA + r * LDST + k4 * 4) = o;
    }
    __syncthreads();

    // S4-S5 it0 aggr-ha (+fused U0 colsum on S5)
    A = An; An = ldA(P.Wp, 7, tid);
    mlp_stage<2, false, false>(A, HA, T0, biasL + 896, nullptr, nullptr, nullptr, n0, l15, q);
    __syncthreads();
    A = An; An = ldA(P.Wp, 2, tid);
    mlp_stage<2, false, true>(A, T0, T1, biasL + 1024, nullptr, meanP, P.pU0 + blk * 128, n0, l15, q);
    __syncthreads();
    // S6 self-ha L0 (independent of partner -> overlap psync2)
    A = An; An = ldA(P.Wp, 3, tid);
    mlp_stage<2, false, false>(A, HA, T0, biasL + 384, nullptr, nullptr, nullptr, n0, l15, q);
    __syncthreads();
    psync(myf, prf, 2u);
    if (tid < 128)
        meanP[tid] = (meanP[tid] + P.pU0[prt * 128 + tid]) * (1.f / 64.f);
    __syncthreads();
    // S7-S9 it0 comb-ha ; HA := ha2
    A = An; An = ldA(P.Wp, 4, tid);
    mlp_stage<2, true , false>(A, T0, T1, biasL + 512, meanQ, nullptr, nullptr, n0, l15, q);
    __syncthreads();
    A = An; An = ldA(P.Wp, 5, tid);
    mlp_stage<2, false, false>(A, T1, T0, biasL + 640, nullptr, nullptr, nullptr, n0, l15, q);
    __syncthreads();
    A = An; An = ldA(P.Wp, 8, tid);
    mlp_stage<2, false, false>(A, T0, HA, biasL + 768, nullptr, nullptr, nullptr, n0, l15, q);
    __syncthreads();
    // S10-S13 it0 comb-hu ; HU := hu2
    A = An; An = ldA(P.Wp, 9, tid);
    mlp_stage<1, false, false>(A, HU, T0, biasL + 1152, nullptr, nullptr, nullptr, n0, l15, q);
    __syncthreads();
    A = An; An = ldA(P.Wp, 10, tid);
    mlp_stage<1, true , false>(A, T0, T1, biasL + 1280, meanP, nullptr, nullptr, n0, l15, q);
    __syncthreads();
    A = An; An = ldA(P.Wp, 11, tid);
    mlp_stage<1, false, false>(A, T1, T0, biasL + 1408, nullptr, nullptr, nullptr, n0, l15, q);
    __syncthreads();
    A = An; An = ldA(P.Wp, 0, tid);
    mlp_stage<1, false, false>(A, T0, HU, biasL + 1536, nullptr, nullptr, nullptr, n0, l15, q);
    __syncthreads();

    // S14-S15 it1 aggr-hu2 (+fused A1 colsum on S15; it1 cu-side is dead)
    A = An; An = ldA(P.Wp, 1, tid);
    mlp_stage<1, false, false>(A, HU, T0, biasL + 128, nullptr, nullptr, nullptr, n0, l15, q);
    __syncthreads();
    A = An; An = ldA(P.Wp, 2, tid);
    mlp_stage<1, false, true>(A, T0, T1, biasL + 256, nullptr, meanQ, P.pA1 + blk * 128, n0, l15, q);
    __syncthreads();
    // S16 self-ha2 L0 (overlap psync3)
    A = An; An = ldA(P.Wp, 3, tid);
    mlp_stage<2, false, false>(A, HA, T0, biasL + 384, nullptr, nullptr, nullptr, n0, l15, q);
    __syncthreads();
    psync(myf, prf, 3u);
    if (tid < 128)
        meanQ[tid] = (meanQ[tid] + P.pA1[prt * 128 + tid]) * (1.f / 32.f);
    __syncthreads();
    // S17-S19 it1 comb-ha2 -> T1   (chain 3 -> 4 -> 5)
    A = An; An = ldA(P.Wp, 4, tid);
    mlp_stage<2, true , false>(A, T0, T1, biasL + 512, meanQ, nullptr, nullptr, n0, l15, q);
    __syncthreads();
    A = An; An = ldA(P.Wp, 5, tid);
    mlp_stage<2, false, false>(A, T1, T0, biasL + 640, nullptr, nullptr, nullptr, n0, l15, q);
    __syncthreads();
    A = An;
    mlp_stage<2, false, false>(A, T0, T1, biasL + 768, nullptr, nullptr, nullptr, n0, l15, q);
    __syncthreads();

    // ---- final: out = normalize(T1 @ Wn + bn); 32 rows x 16 cols = 512 ----
    float* WnS = (float*)T0;                               // 8 KB <= T0
    *(float4*)(WnS + tid * 4) = *(const float4*)(P.Wn + tid * 4);
    __syncthreads();
    {
        const int row = tid >> 4, j = tid & 15;
        float acc = P.bn[j];
        const ushort* h = T1 + row * LDST;
#pragma unroll 8
        for (int k = 0; k < 128; ++k) acc += bf2f(h[k]) * WnS[k * 16 + j];
        const float other = __shfl_xor(acc, 8);            // re<->im partner, same wave
        const float mag = sqrtf(acc * acc + other * other);
        P.out[(size_t)(b * 64 + half * 32 + row) * 16 + j] = acc / mag;
    }
}

extern "C" void kernel_launch(void* const* d_in, const int* in_sizes, int n_in,
                              void* d_out, int out_size, void* d_ws, size_t ws_size,
                              hipStream_t stream)
{
    GP P;
    P.uf    = (const float*)d_in[0];
    P.noise = (const float*)d_in[1];
    const float* W_ue = (const float*)d_in[6];
    P.b_ue  = (const float*)d_in[7];
    P.W_t   = (const float*)d_in[8];
    P.b_t   = (const float*)d_in[9];
    const float* caW[3] = {(const float*)d_in[10], (const float*)d_in[12], (const float*)d_in[14]};
    const float* cab[3] = {(const float*)d_in[11], (const float*)d_in[13], (const float*)d_in[15]};
    const float* cuW[3] = {(const float*)d_in[16], (const float*)d_in[18], (const float*)d_in[20]};
    const float* cub[3] = {(const float*)d_in[17], (const float*)d_in[19], (const float*)d_in[21]};
    P.Wn  = (const float*)d_in[22];
    P.bn  = (const float*)d_in[23];
    P.out = (float*)d_out;

    PrepP Q;
    Q.Wm[0]  = caW[0]; Q.Wm[1]  = caW[0] + 16384;
    Q.Wm[2]  = caW[1]; Q.Wm[3]  = caW[1] + 16384;
    Q.Wm[4]  = caW[2]; Q.Wm[5]  = caW[2] + 16384;
    Q.Wm[6]  = cuW[0]; Q.Wm[7]  = cuW[0] + 16384;
    Q.Wm[8]  = cuW[1]; Q.Wm[9]  = cuW[1] + 16384;
    Q.Wm[10] = cuW[2]; Q.Wm[11] = cuW[2] + 16384;
    Q.Wm[12] = W_ue;
    P.bias6[0] = cab[0]; P.bias6[1] = cab[1]; P.bias6[2] = cab[2];
    P.bias6[3] = cub[0]; P.bias6[4] = cub[1]; P.bias6[5] = cub[2];

    char* w = (char*)d_ws;
    P.flg = (unsigned*)w;                       // 256 flags, 128 B apart (32 KB)
    P.pE  = (float*)(w + 32768);                // 4 partial arrays, 256*128 f each
    P.pA0 = P.pE  + 256 * 128;
    P.pU0 = P.pA0 + 256 * 128;
    P.pA1 = P.pU0 + 256 * 128;
    ushort* Wp = (ushort*)(w + 32768 + 4 * 256 * 128 * 4);   // 13 * 32 KB packed weights
    Q.Wp = Wp;
    Q.flg = P.flg;
    P.Wp = Wp;

    k_prep<<<dim3(52), dim3(512), 0, stream>>>(Q);   // also zeroes flags
    k_gnn<<<dim3(256), dim3(512), 0, stream>>>(P);
}